// Round 1
// baseline (115.301 us; speedup 1.0000x reference)
//
#include <hip/hip_runtime.h>
#include <hip/hip_bf16.h>
#include <hip/hip_fp16.h>

typedef __attribute__((ext_vector_type(8))) short short8;     // bf16x8 frag
typedef __attribute__((ext_vector_type(8))) _Float16 half8;   // f16x8 frag
typedef __attribute__((ext_vector_type(4))) float f32x4;      // acc frag
typedef unsigned short u16;
typedef unsigned int u32;

#define LOG2E 1.44269504088896f

__device__ __forceinline__ u16 f2bf(float f) {
  u32 u = __builtin_bit_cast(u32, f);
  u += 0x7fffu + ((u >> 16) & 1u);   // RNE; inputs are finite positive
  return (u16)(u >> 16);
}
__device__ __forceinline__ u16 f2h(float f) {
  _Float16 h = (_Float16)f;
  return __builtin_bit_cast(u16, h);
}

// ---------------------------------------------------------------------------
// K0: prep. xT[b][n][c] (f16) from x[b][c][n] (f32); W_all f16 [320][256]
// (rows 0-31 Wf, 32-63 Wg, 64-319 Wh); b_all f32 [320].
// ---------------------------------------------------------------------------
__global__ void k_prep(const float* __restrict__ x,
                       const float* __restrict__ Wf, const float* __restrict__ bfp,
                       const float* __restrict__ Wg, const float* __restrict__ bgp,
                       const float* __restrict__ Wh, const float* __restrict__ bhp,
                       u16* __restrict__ xT, u16* __restrict__ Wall,
                       float* __restrict__ ball)
{
  int bid = blockIdx.x, t = threadIdx.x;
  if (bid < 1024) {
    __shared__ u16 tile[64][68];
    int b = bid >> 8, c0 = ((bid >> 6) & 3) << 6, n0 = (bid & 63) << 6;
#pragma unroll
    for (int r = 0; r < 4; ++r) {
      int cl = (t >> 4) + r * 16, nl = (t & 15) * 4;
      const float4 v = *(const float4*)&x[(size_t)(b * 256 + c0 + cl) * 4096 + n0 + nl];
      tile[cl][nl + 0] = f2h(v.x); tile[cl][nl + 1] = f2h(v.y);
      tile[cl][nl + 2] = f2h(v.z); tile[cl][nl + 3] = f2h(v.w);
    }
    __syncthreads();
#pragma unroll
    for (int r = 0; r < 4; ++r) {
      int nl = (t >> 4) + r * 16, cl = (t & 15) * 4;
      ushort4 o;
      o.x = tile[cl + 0][nl]; o.y = tile[cl + 1][nl];
      o.z = tile[cl + 2][nl]; o.w = tile[cl + 3][nl];
      *(ushort4*)&xT[(size_t)(b * 4096 + n0 + nl) * 256 + c0 + cl] = o;
    }
  } else {
    int wb = bid - 1024;                 // 0..79
    int e = wb * 1024 + t * 4;           // element in W_all (320*256)
    int r = e >> 8, c = e & 255;
    const float* src = (r < 32) ? (Wf + r * 256 + c)
                     : (r < 64) ? (Wg + (r - 32) * 256 + c)
                                : (Wh + (r - 64) * 256 + c);
    float4 v = *(const float4*)src;
    ushort4 o; o.x = f2h(v.x); o.y = f2h(v.y); o.z = f2h(v.z); o.w = f2h(v.w);
    *(ushort4*)&Wall[e] = o;
    if (wb == 0 && t < 80) {
#pragma unroll
      for (int i = 0; i < 4; ++i) {
        int idx = t * 4 + i;
        ball[idx] = (idx < 32) ? bfp[idx] : (idx < 64) ? bgp[idx - 32] : bhp[idx - 64];
      }
    }
  }
}

// ---------------------------------------------------------------------------
// K1: projections via f16 MFMA.  Y = W_all * x + b_all.
//  FG mode (rows 0-63):  D[r][n] -> kmat[b][n][k] (r<32), q[b][n][k] (r>=32), f16
//  H  mode (rows 64-319): D[n][r] -> hbf[b][r-64][n], bf16
// ---------------------------------------------------------------------------
__global__ __launch_bounds__(256, 4)
void k_proj(const u16* __restrict__ xT, const u16* __restrict__ Wall,
            const float* __restrict__ ball,
            u16* __restrict__ q, u16* __restrict__ kmat, u16* __restrict__ hbf)
{
  int bid = blockIdx.x, t = threadIdx.x;
  int w = t >> 6, l = t & 63, lg = l >> 4, li = l & 15;
  f32x4 Z = {0.f, 0.f, 0.f, 0.f};
  if (bid < 256) {        // ---- FG ----
    int b = bid >> 6, n0 = (bid & 63) << 6;
    int rbase = w * 16;
    half8 aw[8];
#pragma unroll
    for (int kk = 0; kk < 8; ++kk)
      aw[kk] = *(const half8*)&Wall[(rbase + li) * 256 + kk * 32 + lg * 8];
    float bias[4];
#pragma unroll
    for (int j = 0; j < 4; ++j) bias[j] = ball[rbase + 4 * lg + j];
#pragma unroll
    for (int nn = 0; nn < 4; ++nn) {
      int n = n0 + nn * 16 + li;
      f32x4 acc = Z;
#pragma unroll
      for (int kk = 0; kk < 8; ++kk) {
        half8 bx = *(const half8*)&xT[(size_t)(b * 4096 + n) * 256 + kk * 32 + lg * 8];
        acc = __builtin_amdgcn_mfma_f32_16x16x32_f16(aw[kk], bx, acc, 0, 0, 0);
      }
      ushort4 o;
      o.x = f2h(acc[0] + bias[0]); o.y = f2h(acc[1] + bias[1]);
      o.z = f2h(acc[2] + bias[2]); o.w = f2h(acc[3] + bias[3]);
      u16* dst = (rbase < 32)
               ? (kmat + (size_t)(b * 4096 + n) * 32 + rbase + 4 * lg)
               : (q    + (size_t)(b * 4096 + n) * 32 + (rbase - 32) + 4 * lg);
      *(ushort4*)dst = o;
    }
  } else {                // ---- H ----
    int hb = bid - 256;
    int b = hb >> 8, rt = (hb >> 6) & 3, n0 = (hb & 63) << 6;
    int r0 = 64 + rt * 64;
    int nbase = n0 + w * 16;
    half8 ax[8];
#pragma unroll
    for (int kk = 0; kk < 8; ++kk)
      ax[kk] = *(const half8*)&xT[(size_t)(b * 4096 + nbase + li) * 256 + kk * 32 + lg * 8];
#pragma unroll
    for (int rr = 0; rr < 4; ++rr) {
      int r = r0 + rr * 16 + li;
      f32x4 acc = Z;
#pragma unroll
      for (int kk = 0; kk < 8; ++kk) {
        half8 bw = *(const half8*)&Wall[r * 256 + kk * 32 + lg * 8];
        acc = __builtin_amdgcn_mfma_f32_16x16x32_f16(ax[kk], bw, acc, 0, 0, 0);
      }
      float bias = ball[r];
      ushort4 o;
      o.x = f2bf(acc[0] + bias); o.y = f2bf(acc[1] + bias);
      o.z = f2bf(acc[2] + bias); o.w = f2bf(acc[3] + bias);
      *(ushort4*)&hbf[(size_t)(b * 256 + r - 64) * 4096 + nbase + 4 * lg] = o;
    }
  }
}

// ---------------------------------------------------------------------------
// K2: attention. BM=64 query rows per block, BN=64 keys per iter, 8 waves.
//  S phase: wave w -> (msub=w&3, nh=w>>2): two 16x16 f16 MFMAs (K=dk=32).
//  P~ = exp(S) -> bf16 -> swizzled LDS [64][64].
//  PV phase: wave w -> (csub=w&3, kh=w>>2): 4x4 bf16 MFMAs, V frags straight
//  from global (unique per wave -> no duplication). acc merged across kh at end.
//  Row sums accumulated in fp32 -> divide in epilogue (no softmax stats pass).
// ---------------------------------------------------------------------------
__global__ __launch_bounds__(512, 2)
void k_attn(const u16* __restrict__ q, const u16* __restrict__ kmat,
            const u16* __restrict__ hbf, const float* __restrict__ xin,
            const float* __restrict__ gam, float* __restrict__ out)
{
  __shared__ __align__(16) u16 Pl[64 * 64];     // 8 KB, XOR-swizzled
  __shared__ float mrg[2 * 4096];               // 32 KB, kh-merge staging
  __shared__ float sums[64];

  int bid = blockIdx.x, t = threadIdx.x;
  // XCD-aware: bid%8 fixes batch pair -> each XCD sees one batch's K/V in L2
  int b = (bid >> 1) & 3;
  int mt = ((bid >> 3) << 1) | (bid & 1);
  int m0 = mt << 6;
  int w = t >> 6, l = t & 63, lg = l >> 4, li = l & 15;
  int msub = w & 3, nh = w >> 2;     // S roles
  int csub = msub,  kh = nh;        // PV roles (same bits)

  const u16* qb = q    + (size_t)b * 4096 * 32;
  const u16* kb = kmat + (size_t)b * 4096 * 32;
  const u16* hb = hbf  + (size_t)b * 256 * 4096;

  half8 aQ = *(const half8*)&qb[(m0 + msub * 16 + li) * 32 + lg * 8];

  f32x4 Z = {0.f, 0.f, 0.f, 0.f};
  f32x4 acc[4][4];
#pragma unroll
  for (int mi = 0; mi < 4; ++mi)
#pragma unroll
    for (int ci = 0; ci < 4; ++ci) acc[mi][ci] = Z;
  float vsum[4] = {0.f, 0.f, 0.f, 0.f};

  // prefetch iter 0
  half8 kf0 = *(const half8*)&kb[((nh * 2 + 0) * 16 + li) * 32 + lg * 8];
  half8 kf1 = *(const half8*)&kb[((nh * 2 + 1) * 16 + li) * 32 + lg * 8];
  short8 vb[4];
#pragma unroll
  for (int ff = 0; ff < 4; ++ff)
    vb[ff] = *(const short8*)&hb[(size_t)(csub * 64 + ff * 16 + li) * 4096 + kh * 32 + lg * 8];

  for (int it = 0; it < 64; ++it) {
    int n0 = it * 64;
    int n1 = (n0 + 64) & 4095;   // wrap: iter 63 prefetch is harmless/unused

    f32x4 s0 = __builtin_amdgcn_mfma_f32_16x16x32_f16(aQ, kf0, Z, 0, 0, 0);
    f32x4 s1 = __builtin_amdgcn_mfma_f32_16x16x32_f16(aQ, kf1, Z, 0, 0, 0);

    // prefetch next K frags (stay in flight across barriers)
    kf0 = *(const half8*)&kb[(n1 + (nh * 2 + 0) * 16 + li) * 32 + lg * 8];
    kf1 = *(const half8*)&kb[(n1 + (nh * 2 + 1) * 16 + li) * 32 + lg * 8];

    u16 pu[8];
#pragma unroll
    for (int j = 0; j < 4; ++j) {
      float p0 = exp2f(s0[j] * LOG2E);
      float p1 = exp2f(s1[j] * LOG2E);
      vsum[j] += p0 + p1;
      pu[j]     = f2bf(p0);
      pu[4 + j] = f2bf(p1);
    }

    // barrier A: all waves done reading Pl (prev iter) before overwrite
    asm volatile("s_waitcnt lgkmcnt(0)" ::: "memory");
    __builtin_amdgcn_s_barrier();

#pragma unroll
    for (int s = 0; s < 2; ++s) {
      int nc = (nh * 2 + s) * 16 + li;
#pragma unroll
      for (int j = 0; j < 4; ++j) {
        int m = msub * 16 + 4 * lg + j;
        Pl[m * 64 + (((nc >> 3) ^ (m & 7)) << 3) + (nc & 7)] = pu[s * 4 + j];
      }
    }

    // barrier B: P writes visible
    asm volatile("s_waitcnt lgkmcnt(0)" ::: "memory");
    __builtin_amdgcn_s_barrier();

    short8 pa[4];
#pragma unroll
    for (int mi = 0; mi < 4; ++mi) {
      int m = mi * 16 + li;
      int blk = (kh * 4 + lg) ^ (m & 7);
      pa[mi] = *(const short8*)&Pl[m * 64 + blk * 8];
    }
#pragma unroll
    for (int mi = 0; mi < 4; ++mi)
#pragma unroll
      for (int ci = 0; ci < 4; ++ci)
        acc[mi][ci] = __builtin_amdgcn_mfma_f32_16x16x32_bf16(pa[mi], vb[ci], acc[mi][ci], 0, 0, 0);

    // prefetch next V frags
#pragma unroll
    for (int ff = 0; ff < 4; ++ff)
      vb[ff] = *(const short8*)&hb[(size_t)(csub * 64 + ff * 16 + li) * 4096 + n1 + kh * 32 + lg * 8];
  }

  // ---- epilogue ----
#pragma unroll
  for (int j = 0; j < 4; ++j) {
    float v = vsum[j];
    v += __shfl_xor(v, 1); v += __shfl_xor(v, 2);
    v += __shfl_xor(v, 4); v += __shfl_xor(v, 8);
    vsum[j] = v;
  }
  int mrow = msub * 16 + 4 * lg;
  if (nh == 0 && li == 0) {
#pragma unroll
    for (int j = 0; j < 4; ++j) sums[mrow + j] = vsum[j];
  }
  if (w == 4 || w == 5) {
#pragma unroll
    for (int mi = 0; mi < 4; ++mi)
#pragma unroll
      for (int ci = 0; ci < 4; ++ci)
#pragma unroll
        for (int j = 0; j < 4; ++j)
          mrg[(w - 4) * 4096 + (mi * 16 + ci * 4 + j) * 64 + l] = acc[mi][ci][j];
  }
  __syncthreads();
  if (nh == 1 && li == 0) {
#pragma unroll
    for (int j = 0; j < 4; ++j) sums[mrow + j] += vsum[j];
  }
  if (w == 0 || w == 1) {
#pragma unroll
    for (int mi = 0; mi < 4; ++mi)
#pragma unroll
      for (int ci = 0; ci < 4; ++ci)
#pragma unroll
        for (int j = 0; j < 4; ++j)
          acc[mi][ci][j] += mrg[w * 4096 + (mi * 16 + ci * 4 + j) * 64 + l];
  }
  __syncthreads();
  if (t < 64) sums[t] = 1.0f / sums[t];
  if (w == 6 || w == 7) {
#pragma unroll
    for (int mi = 0; mi < 4; ++mi)
#pragma unroll
      for (int ci = 0; ci < 4; ++ci)
#pragma unroll
        for (int j = 0; j < 4; ++j)
          mrg[(w - 6) * 4096 + (mi * 16 + ci * 4 + j) * 64 + l] = acc[mi][ci][j];
  }
  __syncthreads();
  if (w == 2 || w == 3) {
#pragma unroll
    for (int mi = 0; mi < 4; ++mi)
#pragma unroll
      for (int ci = 0; ci < 4; ++ci)
#pragma unroll
        for (int j = 0; j < 4; ++j)
          acc[mi][ci][j] += mrg[(w - 2) * 4096 + (mi * 16 + ci * 4 + j) * 64 + l];
  }
  if (w < 4) {
    float gamma = gam[0];
    float* ob = out + (size_t)b * 256 * 4096;
    const float* xb = xin + (size_t)b * 256 * 4096;
#pragma unroll
    for (int mi = 0; mi < 4; ++mi) {
      float inv[4];
#pragma unroll
      for (int j = 0; j < 4; ++j) inv[j] = sums[mi * 16 + 4 * lg + j];
#pragma unroll
      for (int ci = 0; ci < 4; ++ci) {
        int c = csub * 64 + ci * 16 + li;
        size_t base = (size_t)c * 4096 + m0 + mi * 16 + 4 * lg;
        float4 xv = *(const float4*)&xb[base];
        float4 ov;
        ov.x = gamma * acc[mi][ci][0] * inv[0] + xv.x;
        ov.y = gamma * acc[mi][ci][1] * inv[1] + xv.y;
        ov.z = gamma * acc[mi][ci][2] * inv[2] + xv.z;
        ov.w = gamma * acc[mi][ci][3] * inv[3] + xv.w;
        *(float4*)&ob[base] = ov;
      }
    }
  }
}

// ---------------------------------------------------------------------------
extern "C" void kernel_launch(void* const* d_in, const int* in_sizes, int n_in,
                              void* d_out, int out_size, void* d_ws, size_t ws_size,
                              hipStream_t stream)
{
  const float* x   = (const float*)d_in[0];
  const float* Wf  = (const float*)d_in[1];
  const float* bfp = (const float*)d_in[2];
  const float* Wg  = (const float*)d_in[3];
  const float* bgp = (const float*)d_in[4];
  const float* Wh  = (const float*)d_in[5];
  const float* bhp = (const float*)d_in[6];
  const float* gam = (const float*)d_in[7];
  float* out = (float*)d_out;

  char* ws = (char*)d_ws;
  u16*   xT   = (u16*)(ws);                  // 8,388,608 B  f16 [4][4096][256]
  u16*   Wall = (u16*)(ws + 8388608);        //   163,840 B  f16 [320][256]
  float* ball = (float*)(ws + 8552448);      //     2,048 B  f32 [320]
  u16*   q    = (u16*)(ws + 8554496);        // 2,097,152 B  f16 [4][4096][32]  (g)
  u16*   km   = (u16*)(ws + 10651648);       // 2,097,152 B  f16 [4][4096][32]  (f)
  u16*   hbf  = (u16*)(ws + 12748800);       // 8,388,608 B  bf16 [4][256][4096] (h)

  k_prep<<<dim3(1104), dim3(256), 0, stream>>>(x, Wf, bfp, Wg, bgp, Wh, bhp, xT, Wall, ball);
  k_proj<<<dim3(1280), dim3(256), 0, stream>>>(xT, Wall, ball, q, km, hbf);
  k_attn<<<dim3(256),  dim3(512), 0, stream>>>(q, km, hbf, x, gam, out);
}